// Round 1
// baseline (391.049 us; speedup 1.0000x reference)
//
#include <hip/hip_runtime.h>

// PillarQueryAndGroup: three dense-domain unique/rank ops via bitmap+popcount
// prefix sum, plus per-point feature assembly (gathers collapse to per-point
// math since f_center[inv[i]] is point i's own bin center).

namespace {
constexpr int   Hc  = 1440, Wc = 1440;
constexpr float Pf  = 0.075f, VZf = 0.25f, VTf = 0.05f;
constexpr int   GZi = 32, GTi = 10;
constexpr float ZCf = 4.0f, TZCf = 5.0f;

// Bitmap layout: three regions concatenated, each padded to 256-word chunks.
// Region A (flat2): domain 2*1440*1440 = 4,147,200 bits = 64,800 words -> pad 65,024 (254 chunks)
// Region B (flat3): *32 -> 132,710,400 bits = 2,073,600 words (8,100 chunks exactly)
// Region C (flatt): *10 ->  41,472,000 bits =   648,000 words -> pad 648,192 (2,532 chunks)
constexpr unsigned REGB_WORD  = 65024u;
constexpr unsigned REGC_WORD  = 2138624u;   // 65,024 + 2,073,600
constexpr unsigned TOT_WORDS  = 2786816u;   // REGC_WORD + 648,192
constexpr unsigned N_CHUNKS   = 10886u;     // TOT_WORDS / 256
constexpr unsigned REGB_CHUNK = 254u;
constexpr unsigned REGC_CHUNK = 8354u;
}

__device__ __forceinline__ void compute_bins(const float* xyzt, int i, int cnt0,
    int& bb, int& ix, int& iy, int& iz, int& it,
    float& x, float& y, float& z, float& t) {
  const float* p = xyzt + (size_t)i * 5;
  x = p[0]; y = p[1]; z = p[2]; t = p[4];
  ix = (int)(x / Pf);  iy = (int)(y / Pf);   // IEEE div matches np reference
  iz = (int)(z / VZf); it = (int)(t / VTf);
  bb = (i >= cnt0) ? 1 : 0;
}

// Fill the three points_coords arrays with -1.0f (rows past #unique stay -1).
__global__ void fill_neg1_kernel(float* out, int n) {
  size_t idx = (size_t)blockIdx.x * blockDim.x + threadIdx.x;
  size_t nn = (size_t)n;
  size_t n3 = 3 * nn, n7 = 7 * nn, tot = 11 * nn;
  if (idx >= tot) return;
  size_t o;
  if (idx < n3)      o = idx;                   // points_coords   @ 0,    3n
  else if (idx < n7) o = 74 * nn + (idx - n3);  // points_coords_Z @ 74n,  4n
  else               o = 149 * nn + (idx - n7); // points_coords_T @ 149n, 4n
  out[o] = -1.0f;
}

__global__ void scatter_bits_kernel(const float* xyzt, const int* cnt, int n,
                                    unsigned long long* bitmap) {
  int i = blockIdx.x * blockDim.x + threadIdx.x;
  if (i >= n) return;
  int cnt0 = cnt[0];
  int bb, ix, iy, iz, it; float x, y, z, t;
  compute_bins(xyzt, i, cnt0, bb, ix, iy, iz, it, x, y, z, t);
  unsigned f2 = (unsigned)((bb * Hc + iy) * Wc + ix);
  unsigned f3 = f2 * (unsigned)GZi + (unsigned)iz;
  unsigned ft = f2 * (unsigned)GTi + (unsigned)it;
  atomicOr(&bitmap[f2 >> 6], 1ull << (f2 & 63));
  atomicOr(&bitmap[REGB_WORD + (f3 >> 6)], 1ull << (f3 & 63));
  atomicOr(&bitmap[REGC_WORD + (ft >> 6)], 1ull << (ft & 63));
}

// Per 256-word chunk: popcount each word, exclusive scan within chunk,
// emit per-word prefix and chunk total.
__global__ void scan1_kernel(const unsigned long long* bitmap,
                             unsigned* wordPrefix, unsigned* chunkSums) {
  __shared__ unsigned s[256];
  unsigned tid = threadIdx.x;
  unsigned w = blockIdx.x * 256u + tid;
  unsigned pc = (unsigned)__popcll(bitmap[w]);
  s[tid] = pc;
  __syncthreads();
  for (int o = 1; o < 256; o <<= 1) {
    unsigned v = (tid >= (unsigned)o) ? s[tid - o] : 0u;
    __syncthreads();
    s[tid] += v;
    __syncthreads();
  }
  wordPrefix[w] = s[tid] - pc;          // exclusive within chunk
  if (tid == 255) chunkSums[blockIdx.x] = s[255];
}

// Single-block exclusive scan over chunk sums (10,886 entries, 43 tiles).
__global__ void scan2_kernel(const unsigned* chunkSums, unsigned* chunkPrefix) {
  __shared__ unsigned s[256];
  __shared__ unsigned carry_s;
  unsigned tid = threadIdx.x;
  if (tid == 0) carry_s = 0;
  __syncthreads();
  const unsigned tiles = (N_CHUNKS + 255u) / 256u;
  for (unsigned tile = 0; tile < tiles; ++tile) {
    unsigned idx = tile * 256u + tid;
    unsigned v = (idx < N_CHUNKS) ? chunkSums[idx] : 0u;
    unsigned base = carry_s;
    s[tid] = v;
    __syncthreads();
    for (int o = 1; o < 256; o <<= 1) {
      unsigned vv = (tid >= (unsigned)o) ? s[tid - o] : 0u;
      __syncthreads();
      s[tid] += vv;
      __syncthreads();
    }
    if (idx < N_CHUNKS) chunkPrefix[idx] = base + s[tid] - v;
    unsigned tot = s[255];
    __syncthreads();
    if (tid == 0) carry_s = base + tot;
    __syncthreads();
  }
}

// One wave (64 lanes) per point: lanes copy the 64 point_features, lanes 0-5
// write the 6 tail columns, lane 0 computes ranks and scatters coords + inv.
__global__ __launch_bounds__(256) void finalize_kernel(
    const float* xyzt, const int* cnt, const float* pf, int n,
    const unsigned long long* bitmap, const unsigned* wordPrefix,
    const unsigned* chunkPrefix, float* out) {
  int wave = threadIdx.x >> 6;
  int lane = threadIdx.x & 63;
  int i = blockIdx.x * 4 + wave;
  if (i >= n) return;
  int cnt0 = cnt[0];
  int bb, ix, iy, iz, it; float x, y, z, t;
  compute_bins(xyzt, i, cnt0, bb, ix, iy, iz, it, x, y, z, t);

  size_t nn = (size_t)n;
  const size_t o_coords  = 0,         o_inv2 = 3 * nn,   o_feat  = 4 * nn;
  const size_t o_coordsZ = 74 * nn,   o_inv3 = 78 * nn,  o_zfeat = 79 * nn;
  const size_t o_coordsT = 149 * nn,  o_invt = 153 * nn, o_tfeat = 154 * nn;

  // point_features copy (cols 0..63 of all three feature arrays)
  float v = pf[(size_t)i * 64 + lane];
  size_t r = (size_t)i * 70 + lane;
  out[o_feat  + r] = v;
  out[o_zfeat + r] = v;
  out[o_tfeat + r] = v;

  float cx = ((float)ix + 0.5f) * Pf;
  float cy = ((float)iy + 0.5f) * Pf;
  if (lane < 6) {
    float tf, t2;
    switch (lane) {
      case 0:  tf = x;      t2 = x;        break;
      case 1:  tf = y;      t2 = y;        break;
      case 2:  tf = z;      t2 = t;        break;
      case 3:  tf = x - cx; t2 = x - cx;   break;
      case 4:  tf = y - cy; t2 = y - cy;   break;
      default: tf = z - ZCf; t2 = t - TZCf; break;
    }
    size_t rr = (size_t)i * 70 + 64 + lane;
    out[o_feat  + rr] = tf;
    out[o_zfeat + rr] = tf;   // z_features == features (vx=ix, vy=iy, Z_CENTER)
    out[o_tfeat + rr] = t2;
  }

  if (lane == 0) {
    unsigned f2 = (unsigned)((bb * Hc + iy) * Wc + ix);
    unsigned f3 = f2 * (unsigned)GZi + (unsigned)iz;
    unsigned ft = f2 * (unsigned)GTi + (unsigned)it;
    auto rank = [&](unsigned wordOff, unsigned vv) -> unsigned {
      unsigned w = wordOff + (vv >> 6);
      unsigned bit = vv & 63u;
      return chunkPrefix[w >> 8] + wordPrefix[w] +
             (unsigned)__popcll(bitmap[w] & ((1ull << bit) - 1ull));
    };
    unsigned r2 = rank(0u, f2);                                  // base A = 0
    unsigned r3 = rank(REGB_WORD, f3) - chunkPrefix[REGB_CHUNK];
    unsigned rt = rank(REGC_WORD, ft) - chunkPrefix[REGC_CHUNK];
    out[o_inv2 + i] = (float)r2;
    out[o_inv3 + i] = (float)r3;
    out[o_invt + i] = (float)rt;
    float* pc2 = out + o_coords + (size_t)r2 * 3;
    pc2[0] = (float)bb; pc2[1] = (float)iy; pc2[2] = (float)ix;
    float* pz = out + o_coordsZ + (size_t)r3 * 4;
    pz[0] = (float)bb; pz[1] = (float)iz; pz[2] = (float)iy; pz[3] = (float)ix;
    float* pt = out + o_coordsT + (size_t)rt * 4;
    pt[0] = (float)bb; pt[1] = (float)it; pt[2] = (float)iy; pt[3] = (float)ix;
  }
}

extern "C" void kernel_launch(void* const* d_in, const int* in_sizes, int n_in,
                              void* d_out, int out_size, void* d_ws, size_t ws_size,
                              hipStream_t stream) {
  const float* xyzt = (const float*)d_in[0];
  const int*   cnt  = (const int*)d_in[1];
  const float* pf   = (const float*)d_in[2];
  float* out = (float*)d_out;
  int n = in_sizes[0] / 5;

  // Workspace layout (~33.5 MB): bitmap | wordPrefix | chunkSums | chunkPrefix
  unsigned long long* bitmap = (unsigned long long*)d_ws;
  unsigned* wordPrefix  = (unsigned*)((char*)d_ws + (size_t)TOT_WORDS * 8);
  unsigned* chunkSums   = (unsigned*)((char*)d_ws + (size_t)TOT_WORDS * 8 + (size_t)TOT_WORDS * 4);
  unsigned* chunkPrefix = chunkSums + ((N_CHUNKS + 7u) & ~7u);

  hipMemsetAsync(bitmap, 0, (size_t)TOT_WORDS * 8, stream);

  size_t fill_tot = (size_t)11 * n;
  fill_neg1_kernel<<<(unsigned)((fill_tot + 255) / 256), 256, 0, stream>>>(out, n);

  scatter_bits_kernel<<<(n + 255) / 256, 256, 0, stream>>>(xyzt, cnt, n, bitmap);

  scan1_kernel<<<N_CHUNKS, 256, 0, stream>>>(bitmap, wordPrefix, chunkSums);
  scan2_kernel<<<1, 256, 0, stream>>>(chunkSums, chunkPrefix);

  finalize_kernel<<<(n + 3) / 4, 256, 0, stream>>>(xyzt, cnt, pf, n,
                                                   bitmap, wordPrefix, chunkPrefix, out);
}

// Round 2
// 304.821 us; speedup vs baseline: 1.2829x; 1.2829x over previous
//
#include <hip/hip_runtime.h>

// PillarQueryAndGroup: three dense-domain unique/rank ops via bitmap+popcount
// prefix sum, plus per-point feature assembly (gathers collapse to per-point
// math since f_center[inv[i]] is point i's own bin center).
//
// R1: split wave-per-point finalize into linear float2 features kernel +
// thread-per-point coords kernel; barrier-free shuffle scan1; blocked scan2;
// float4 -1 fill.

namespace {
constexpr int   Hc  = 1440, Wc = 1440;
constexpr float Pf  = 0.075f, VZf = 0.25f, VTf = 0.05f;
constexpr int   GZi = 32, GTi = 10;
constexpr float ZCf = 4.0f, TZCf = 5.0f;

// Bitmap layout: three regions concatenated, each padded to 256-word chunks.
// Region A (flat2): 2*1440*1440 bits = 64,800 words -> pad 65,024 (254 chunks)
// Region B (flat3): *32 -> 2,073,600 words (8,100 chunks exactly)
// Region C (flatt): *10 ->   648,000 words -> pad 648,192 (2,532 chunks)
constexpr unsigned REGB_WORD  = 65024u;
constexpr unsigned REGC_WORD  = 2138624u;   // 65,024 + 2,073,600
constexpr unsigned TOT_WORDS  = 2786816u;   // REGC_WORD + 648,192
constexpr unsigned N_CHUNKS   = 10886u;     // TOT_WORDS / 256
constexpr unsigned REGB_CHUNK = 254u;
constexpr unsigned REGC_CHUNK = 8354u;
}

__device__ __forceinline__ void compute_bins(const float* xyzt, int i, int cnt0,
    int& bb, int& ix, int& iy, int& iz, int& it,
    float& x, float& y, float& z, float& t) {
  const float* p = xyzt + (size_t)i * 5;
  x = p[0]; y = p[1]; z = p[2]; t = p[4];
  ix = (int)(x / Pf);  iy = (int)(y / Pf);   // IEEE div matches np reference
  iz = (int)(z / VZf); it = (int)(t / VTf);
  bb = (i >= cnt0) ? 1 : 0;
}

// Fill the three points_coords arrays with -1.0f, float4-vectorized.
// Requires n % 4 == 0 (n = 200000).
__global__ void fill_neg1_kernel(float4* out4, int n) {
  unsigned idx = blockIdx.x * blockDim.x + threadIdx.x;
  unsigned nq = (unsigned)n / 4u;            // n/4
  unsigned cA = 3u * nq, cB = 4u * nq;       // f4 counts: 3n/4, n, n
  unsigned tot = cA + 2u * cB;
  if (idx >= tot) return;
  size_t o;
  if (idx < cA)            o = idx;                              // @ 0
  else if (idx < cA + cB)  o = (size_t)74 * nq + (idx - cA);     // @ 74n/4
  else                     o = (size_t)149 * nq + (idx - cA - cB); // @ 149n/4
  out4[o] = make_float4(-1.f, -1.f, -1.f, -1.f);
}

__global__ void scatter_bits_kernel(const float* xyzt, const int* cnt, int n,
                                    unsigned long long* bitmap) {
  int i = blockIdx.x * blockDim.x + threadIdx.x;
  if (i >= n) return;
  int cnt0 = cnt[0];
  int bb, ix, iy, iz, it; float x, y, z, t;
  compute_bins(xyzt, i, cnt0, bb, ix, iy, iz, it, x, y, z, t);
  unsigned f2 = (unsigned)((bb * Hc + iy) * Wc + ix);
  unsigned f3 = f2 * (unsigned)GZi + (unsigned)iz;
  unsigned ft = f2 * (unsigned)GTi + (unsigned)it;
  atomicOr(&bitmap[f2 >> 6], 1ull << (f2 & 63));
  atomicOr(&bitmap[REGB_WORD + (f3 >> 6)], 1ull << (f3 & 63));
  atomicOr(&bitmap[REGC_WORD + (ft >> 6)], 1ull << (ft & 63));
}

// One wave per 256-word chunk, barrier-free: each lane popcounts 4 words,
// shuffle-scan across 64 lanes, uint4 store of per-word exclusive prefixes.
__global__ __launch_bounds__(256) void scan1_kernel(
    const unsigned long long* bitmap, unsigned* wordPrefix, unsigned* chunkSums) {
  unsigned tid = threadIdx.x;
  unsigned lane = tid & 63u;
  unsigned chunk = blockIdx.x * 4u + (tid >> 6);
  if (chunk >= N_CHUNKS) return;
  unsigned wbase = chunk * 256u + lane * 4u;
  const ulonglong2* bp = (const ulonglong2*)(bitmap + wbase);
  ulonglong2 w01 = bp[0], w23 = bp[1];
  unsigned p0 = (unsigned)__popcll(w01.x), p1 = (unsigned)__popcll(w01.y);
  unsigned p2 = (unsigned)__popcll(w23.x), p3 = (unsigned)__popcll(w23.y);
  unsigned lsum = p0 + p1 + p2 + p3;
  unsigned x = lsum;
  #pragma unroll
  for (int d = 1; d < 64; d <<= 1) {
    unsigned o = __shfl_up(x, d, 64);
    if ((int)lane >= d) x += o;
  }
  unsigned excl = x - lsum;                  // exclusive across lanes
  uint4 wp;
  wp.x = excl; wp.y = excl + p0; wp.z = excl + p0 + p1; wp.w = excl + p0 + p1 + p2;
  *(uint4*)(wordPrefix + wbase) = wp;
  if (lane == 63u) chunkSums[chunk] = x;     // chunk total
}

// Single-block exclusive scan over 10,886 chunk sums: 43 elements/thread
// serial, one 256-wide block scan, serial prefix write-back.
__global__ void scan2_kernel(const unsigned* chunkSums, unsigned* chunkPrefix) {
  __shared__ unsigned s[256];
  unsigned tid = threadIdx.x;
  const unsigned K = (N_CHUNKS + 255u) / 256u;   // 43
  unsigned base = tid * K;
  unsigned end = min(base + K, N_CHUNKS);
  unsigned sum = 0;
  for (unsigned j = base; j < end; ++j) sum += chunkSums[j];
  s[tid] = sum;
  __syncthreads();
  for (int o = 1; o < 256; o <<= 1) {
    unsigned v = (tid >= (unsigned)o) ? s[tid - o] : 0u;
    __syncthreads();
    s[tid] += v;
    __syncthreads();
  }
  unsigned run = s[tid] - sum;               // exclusive across threads
  for (unsigned j = base; j < end; ++j) {
    unsigned v = chunkSums[j];
    chunkPrefix[j] = run;
    run += v;
  }
}

// Linear float2 kernel over the three n*70 feature arrays.
// idx in [0, 35n): i = idx/35, c2 = idx%35. c2<32 -> pf copy; else tail math.
__global__ __launch_bounds__(256) void features_kernel(
    const float* xyzt, const float* pf, int n, float* out) {
  unsigned idx = blockIdx.x * blockDim.x + threadIdx.x;
  unsigned tot = 35u * (unsigned)n;
  if (idx >= tot) return;
  unsigned i = idx / 35u;
  unsigned c2 = idx - i * 35u;
  size_t nn = (size_t)n;
  float2* f  = (float2*)(out + 4 * nn);      // features  (4n even)
  float2* zf = (float2*)(out + 79 * nn);     // z_features(79n even for n=200k)
  float2* tf = (float2*)(out + 154 * nn);    // t_features
  size_t r = (size_t)i * 35 + c2;
  float2 v, vt;
  if (c2 < 32u) {
    v = ((const float2*)pf)[(size_t)i * 32 + c2];
    vt = v;
  } else {
    const float* p = xyzt + (size_t)i * 5;
    float x = p[0], y = p[1], z = p[2], t = p[4];
    int ix = (int)(x / Pf), iy = (int)(y / Pf);
    float cx = ((float)ix + 0.5f) * Pf, cy = ((float)iy + 0.5f) * Pf;
    if (c2 == 32u)      { v = make_float2(x, y);        vt = v; }
    else if (c2 == 33u) { v = make_float2(z, x - cx);   vt = make_float2(t, x - cx); }
    else                { v = make_float2(y - cy, z - ZCf); vt = make_float2(y - cy, t - TZCf); }
  }
  f[r] = v; zf[r] = v; tf[r] = vt;           // z_features == features
}

// Thread-per-point: 3 rank lookups, write inv (coalesced) + scatter coords.
__global__ __launch_bounds__(256) void coords_kernel(
    const float* xyzt, const int* cnt, int n,
    const unsigned long long* bitmap, const unsigned* wordPrefix,
    const unsigned* chunkPrefix, float* out) {
  int i = blockIdx.x * blockDim.x + threadIdx.x;
  if (i >= n) return;
  int cnt0 = cnt[0];
  int bb, ix, iy, iz, it; float x, y, z, t;
  compute_bins(xyzt, i, cnt0, bb, ix, iy, iz, it, x, y, z, t);

  size_t nn = (size_t)n;
  const size_t o_coords  = 0,        o_inv2 = 3 * nn;
  const size_t o_coordsZ = 74 * nn,  o_inv3 = 78 * nn;
  const size_t o_coordsT = 149 * nn, o_invt = 153 * nn;

  unsigned f2 = (unsigned)((bb * Hc + iy) * Wc + ix);
  unsigned f3 = f2 * (unsigned)GZi + (unsigned)iz;
  unsigned ft = f2 * (unsigned)GTi + (unsigned)it;
  auto rank = [&](unsigned wordOff, unsigned vv) -> unsigned {
    unsigned w = wordOff + (vv >> 6);
    unsigned bit = vv & 63u;
    return chunkPrefix[w >> 8] + wordPrefix[w] +
           (unsigned)__popcll(bitmap[w] & ((1ull << bit) - 1ull));
  };
  unsigned r2 = rank(0u, f2);                                  // base A = 0
  unsigned r3 = rank(REGB_WORD, f3) - chunkPrefix[REGB_CHUNK];
  unsigned rt = rank(REGC_WORD, ft) - chunkPrefix[REGC_CHUNK];
  out[o_inv2 + i] = (float)r2;
  out[o_inv3 + i] = (float)r3;
  out[o_invt + i] = (float)rt;
  float* pc2 = out + o_coords + (size_t)r2 * 3;
  pc2[0] = (float)bb; pc2[1] = (float)iy; pc2[2] = (float)ix;
  float* pz = out + o_coordsZ + (size_t)r3 * 4;
  pz[0] = (float)bb; pz[1] = (float)iz; pz[2] = (float)iy; pz[3] = (float)ix;
  float* pt = out + o_coordsT + (size_t)rt * 4;
  pt[0] = (float)bb; pt[1] = (float)it; pt[2] = (float)iy; pt[3] = (float)ix;
}

extern "C" void kernel_launch(void* const* d_in, const int* in_sizes, int n_in,
                              void* d_out, int out_size, void* d_ws, size_t ws_size,
                              hipStream_t stream) {
  const float* xyzt = (const float*)d_in[0];
  const int*   cnt  = (const int*)d_in[1];
  const float* pf   = (const float*)d_in[2];
  float* out = (float*)d_out;
  int n = in_sizes[0] / 5;

  // Workspace: bitmap (22.3MB) | wordPrefix (11.1MB) | chunkSums | chunkPrefix
  unsigned long long* bitmap = (unsigned long long*)d_ws;
  unsigned* wordPrefix  = (unsigned*)((char*)d_ws + (size_t)TOT_WORDS * 8);
  unsigned* chunkSums   = (unsigned*)((char*)d_ws + (size_t)TOT_WORDS * 12);
  unsigned* chunkPrefix = chunkSums + ((N_CHUNKS + 7u) & ~7u);

  hipMemsetAsync(bitmap, 0, (size_t)TOT_WORDS * 8, stream);

  unsigned fillq = (unsigned)(11 * n / 4);
  fill_neg1_kernel<<<(fillq + 255) / 256, 256, 0, stream>>>((float4*)out, n);

  scatter_bits_kernel<<<(n + 255) / 256, 256, 0, stream>>>(xyzt, cnt, n, bitmap);

  scan1_kernel<<<(N_CHUNKS + 3) / 4, 256, 0, stream>>>(bitmap, wordPrefix, chunkSums);
  scan2_kernel<<<1, 256, 0, stream>>>(chunkSums, chunkPrefix);

  features_kernel<<<(35u * (unsigned)n + 255) / 256, 256, 0, stream>>>(xyzt, pf, n, out);

  coords_kernel<<<(n + 255) / 256, 256, 0, stream>>>(xyzt, cnt, n,
                                                     bitmap, wordPrefix, chunkPrefix, out);
}